// Round 6
// baseline (308.557 us; speedup 1.0000x reference)
//
#include <hip/hip_runtime.h>
#include <hip/hip_bf16.h>
#include <math.h>

#define B_ 64
#define S_ 512
#define D_ 1024
#define H_ 512
#define WSEG 96
#define TSEG 24
#define CSEG 128
#define NSEG (WSEG + TSEG + CSEG) /* 248 */
#define ESEG (TSEG + CSEG + 1)    /* 153 */
#define EPAD 160                  /* ent rows padded per batch */

typedef __bf16 bf16x8 __attribute__((ext_vector_type(8)));
typedef __bf16 bf16x4 __attribute__((ext_vector_type(4)));
typedef float f32x4 __attribute__((ext_vector_type(4)));

#define GL16(g, l)                                                      \
  __builtin_amdgcn_global_load_lds(                                     \
      (const __attribute__((address_space(1))) void*)(g),               \
      (__attribute__((address_space(3))) void*)(l), 16, 0, 0)

__device__ inline float tanh_fast(float x) {
  const float xc = fminf(12.f, fmaxf(-12.f, x));
  const float e = __expf(2.f * xc);
  return (e - 1.f) * __builtin_amdgcn_rcpf(e + 1.f);
}

// ---------------------------------------------------------------------------
// Stage 1a: build CSR token lists per (b, segtype, seg). One block per b.
// ---------------------------------------------------------------------------
__global__ __launch_bounds__(512) void build_csr_kernel(
    const int* __restrict__ wseg, const int* __restrict__ tseg,
    const int* __restrict__ cseg, int* __restrict__ lw, int* __restrict__ lt,
    int* __restrict__ lc, int* __restrict__ meta) {
  __shared__ int wid[S_], tid_[S_], cid[S_];
  __shared__ int cw[WSEG], ct[TSEG], cc[CSEG];
  const int t = threadIdx.x;
  const int b = blockIdx.x;

  const int myw = wseg[b * S_ + t];
  const int myt = tseg[b * S_ + t];
  const int myc = cseg[b * S_ + t];
  wid[t] = myw;
  tid_[t] = myt;
  cid[t] = myc;
  if (t < WSEG) cw[t] = 0;
  if (t < TSEG) ct[t] = 0;
  if (t < CSEG) cc[t] = 0;
  __syncthreads();

  atomicAdd(&cw[myw], 1);
  atomicAdd(&ct[myt], 1);
  atomicAdd(&cc[myc], 1);
  __syncthreads();

  if (t == 0) {
    int r = 0;
    for (int i = 0; i < WSEG; ++i) {
      const int c = cw[i];
      meta[b * NSEG + i] = r | (c << 16);
      cw[i] = r;
      r += c;
    }
    r = 0;
    for (int i = 0; i < TSEG; ++i) {
      const int c = ct[i];
      meta[b * NSEG + WSEG + i] = r | (c << 16);
      ct[i] = r;
      r += c;
    }
    r = 0;
    for (int i = 0; i < CSEG; ++i) {
      const int c = cc[i];
      meta[b * NSEG + WSEG + TSEG + i] = r | (c << 16);
      cc[i] = r;
      r += c;
    }
  }
  __syncthreads();

  int rw = 0, rt = 0, rc = 0;
  for (int s = 0; s < S_; ++s) {
    const int below = (s < t) ? 1 : 0;
    rw += below & (wid[s] == myw);
    rt += below & (tid_[s] == myt);
    rc += below & (cid[s] == myc);
  }
  lw[b * S_ + cw[myw] + rw] = t;
  lt[b * S_ + ct[myt] + rt] = t;
  lc[b * S_ + cc[myc] + rc] = t;
}

// ---------------------------------------------------------------------------
// Stage 1b: ONE-PASS gather-sum. Grid (32 d-slices, B). Block: 256 thr.
// Stage q[b, :, d0:d0+32] in LDS (exactly 64KB), then each wave computes
// rows r = wid, wid+4, ... of the 248 segment sums by register accumulation
// over the CSR token list (lanes: col = lane&31, token-parity = lane>>5).
// q read ONCE from HBM (134MB) vs 3x in the old per-row gather. No atomics.
// ---------------------------------------------------------------------------
__global__ __launch_bounds__(256) void gather_onepass_kernel(
    const float* __restrict__ q, const int* __restrict__ lw,
    const int* __restrict__ lt, const int* __restrict__ lc,
    const int* __restrict__ meta, __bf16* __restrict__ Ah,
    __bf16* __restrict__ Al) {
  __shared__ float qs[S_][32];  // 65536 B
  const int tid = threadIdx.x;
  const int d0 = blockIdx.x * 32;
  const int b = blockIdx.y;
  const float* qb = q + (size_t)b * S_ * D_ + d0;

#pragma unroll
  for (int it = 0; it < 16; ++it) {
    const int idx = it * 256 + tid;
    const int s = idx >> 3, g = idx & 7;
    *(float4*)&qs[s][g * 4] = *(const float4*)(qb + (size_t)s * D_ + g * 4);
  }
  __syncthreads();

  const int wid = tid >> 6, lane = tid & 63;
  const int col = lane & 31, tk = lane >> 5;

  for (int r = wid; r < NSEG; r += 4) {
    const int m = meta[b * NSEG + r];
    const int start = m & 0xFFFF, count = m >> 16;
    const int* list;
    int arow;
    if (r < WSEG) {
      list = lw;
      arow = b * WSEG + r;
    } else if (r < WSEG + TSEG) {
      list = lt;
      arow = B_ * WSEG + b * TSEG + (r - WSEG);
    } else {
      list = lc;
      arow = B_ * (WSEG + TSEG) + b * CSEG + (r - WSEG - TSEG);
    }
    const int* lp = list + b * S_ + start;
    float acc = 0.f;
    for (int i = tk; i < count; i += 2) acc += qs[lp[i]][col];
    acc += __shfl_xor(acc, 32, 64);  // combine even/odd token partial sums
    if (tk == 0) {
      const __bf16 h = (__bf16)acc;
      Ah[(size_t)arow * D_ + d0 + col] = h;
      Al[(size_t)arow * D_ + d0 + col] = (__bf16)(acc - (float)h);
    }
  }
}

// ---------------------------------------------------------------------------
// Stage 1c: transpose weights -> Wt hi/lo bf16 [3][512][1024].
// ---------------------------------------------------------------------------
__global__ __launch_bounds__(256) void prep_w_kernel(
    const float* __restrict__ Ws, const float* __restrict__ Wt_,
    const float* __restrict__ Wc, __bf16* __restrict__ Wth,
    __bf16* __restrict__ Wtl) {
  __shared__ float tile[64][65];
  const int z = blockIdx.z;
  const float* W = (z == 0) ? Ws : ((z == 1) ? Wt_ : Wc);
  const int k0 = blockIdx.y * 64, n0 = blockIdx.x * 64;
  const int tx = threadIdx.x & 63, ty = threadIdx.x >> 6;

#pragma unroll
  for (int i = 0; i < 16; ++i) {
    const int kl = i * 4 + ty;
    tile[kl][tx] = W[(size_t)(k0 + kl) * H_ + n0 + tx];
  }
  __syncthreads();
  __bf16* oh = Wth + (size_t)z * H_ * D_;
  __bf16* ol = Wtl + (size_t)z * H_ * D_;
#pragma unroll
  for (int i = 0; i < 16; ++i) {
    const int nl = i * 4 + ty;
    const float v = tile[tx][nl];
    const __bf16 h = (__bf16)v;
    oh[(size_t)(n0 + nl) * D_ + k0 + tx] = h;
    ol[(size_t)(n0 + nl) * D_ + k0 + tx] = (__bf16)(v - (float)h);
  }
}

// ---------------------------------------------------------------------------
// Stage 2: split-bf16 MFMA GEMM, 128x128 tile, BK=64, tanh epilogue.
// SINGLE launch over all 15872 A rows (flat ws layout -> no overlay race).
// ---------------------------------------------------------------------------
__global__ __launch_bounds__(256) void gemm3_kernel(
    const __bf16* __restrict__ Ah, const __bf16* __restrict__ Al,
    const __bf16* __restrict__ Wth, const __bf16* __restrict__ Wtl,
    __bf16* __restrict__ sub_h, __bf16* __restrict__ sub_l,
    __bf16* __restrict__ ent_h, __bf16* __restrict__ ent_l, int m_offset) {
  __shared__ __align__(16) char smem[65536];
  char* sAh = smem;
  char* sAl = smem + 16384;
  char* sBh = smem + 32768;
  char* sBl = smem + 49152;

  const int tid = threadIdx.x;
  const int wid = tid >> 6;
  const int lane = tid & 63;
  const int m0 = m_offset + blockIdx.y * 128;
  const int n0 = blockIdx.x * 128;
  const int id = (m0 < B_ * WSEG) ? 0 : ((m0 < B_ * (WSEG + TSEG)) ? 1 : 2);

  const __bf16* Bh_g = Wth + (size_t)id * H_ * D_ + (size_t)n0 * D_;
  const __bf16* Bl_g = Wtl + (size_t)id * H_ * D_ + (size_t)n0 * D_;
  const __bf16* Ah_g = Ah + (size_t)m0 * D_;
  const __bf16* Al_g = Al + (size_t)m0 * D_;

  const int rsub = lane >> 3;
  const int csrc = (lane & 7) ^ rsub;

  const int wr = wid >> 1, wc = wid & 1;
  const int arow0 = wr * 64 + (lane & 15);
  const int brow0 = wc * 64 + (lane & 15);
  const int cbase = (lane >> 4) * 16;
  const int sw = (lane & 7) << 4;

  f32x4 acc[4][4] = {};

#pragma unroll 1
  for (int kt = 0; kt < D_ / 64; ++kt) {
    __syncthreads();
    const size_t kofs = (size_t)kt * 64 + (size_t)csrc * 8;
#pragma unroll
    for (int j = 0; j < 4; ++j) {
      const int i = wid * 4 + j;
      const size_t grow = (size_t)(i * 8 + rsub) * D_ + kofs;
      GL16(Ah_g + grow, sAh + i * 1024);
      GL16(Al_g + grow, sAl + i * 1024);
      GL16(Bh_g + grow, sBh + i * 1024);
      GL16(Bl_g + grow, sBl + i * 1024);
    }
    __syncthreads();

#pragma unroll
    for (int ks = 0; ks < 2; ++ks) {
      const int cc = ((cbase + ks * 64) ^ sw);
      bf16x8 ah[4], al_[4], bh[4], bl_[4];
#pragma unroll
      for (int mi = 0; mi < 4; ++mi) {
        const int off = (arow0 + mi * 16) * 128 + cc;
        ah[mi] = *(const bf16x8*)(sAh + off);
        al_[mi] = *(const bf16x8*)(sAl + off);
      }
#pragma unroll
      for (int ni = 0; ni < 4; ++ni) {
        const int off = (brow0 + ni * 16) * 128 + cc;
        bh[ni] = *(const bf16x8*)(sBh + off);
        bl_[ni] = *(const bf16x8*)(sBl + off);
      }
#pragma unroll
      for (int mi = 0; mi < 4; ++mi)
#pragma unroll
        for (int ni = 0; ni < 4; ++ni) {
          acc[mi][ni] = __builtin_amdgcn_mfma_f32_16x16x32_bf16(
              ah[mi], bh[ni], acc[mi][ni], 0, 0, 0);
          acc[mi][ni] = __builtin_amdgcn_mfma_f32_16x16x32_bf16(
              ah[mi], bl_[ni], acc[mi][ni], 0, 0, 0);
          acc[mi][ni] = __builtin_amdgcn_mfma_f32_16x16x32_bf16(
              al_[mi], bh[ni], acc[mi][ni], 0, 0, 0);
        }
    }
  }

  const int rowb = m0 + wr * 64 + (lane >> 4) * 4;
  const int colb = n0 + wc * 64 + (lane & 15);
#pragma unroll
  for (int mi = 0; mi < 4; ++mi)
#pragma unroll
    for (int ni = 0; ni < 4; ++ni) {
      const f32x4 v = acc[mi][ni];
      const int col = colb + ni * 16;
#pragma unroll
      for (int r = 0; r < 4; ++r) {
        const int row = rowb + mi * 16 + r;
        const float val = tanh_fast(v[r]);
        const __bf16 h = (__bf16)val;
        const __bf16 l = (__bf16)(val - (float)h);
        size_t oix;
        __bf16 *oh, *ol;
        if (id == 0) {
          oix = (size_t)row * H_ + col;
          oh = sub_h;
          ol = sub_l;
        } else if (id == 1) {
          const int lr = row - B_ * WSEG;
          const int bb = lr / TSEG;
          const int rr = lr - bb * TSEG;
          oix = ((size_t)bb * EPAD + rr) * H_ + col;
          oh = ent_h;
          ol = ent_l;
        } else {
          const int lr = row - B_ * (WSEG + TSEG);
          const int bb = lr >> 7;
          const int rr = lr & 127;
          oix = ((size_t)bb * EPAD + TSEG + rr) * H_ + col;
          oh = ent_h;
          ol = ent_l;
        }
        oh[oix] = h;
        ol[oix] = l;
      }
    }
}

// Stage 2b: ent row 152 = no_entry (hi/lo, raw); rows 153..159 zeroed.
__global__ __launch_bounds__(512) void ne_fill_kernel(
    const float* __restrict__ ne, __bf16* __restrict__ ent_h,
    __bf16* __restrict__ ent_l) {
  const int h = threadIdx.x;
  const int b = blockIdx.x;
  const float v = ne[h];
  const __bf16 hi = (__bf16)v;
  const __bf16 lo = (__bf16)(v - (float)hi);
  ent_h[((size_t)b * EPAD + 152) * H_ + h] = hi;
  ent_l[((size_t)b * EPAD + 152) * H_ + h] = lo;
#pragma unroll
  for (int r = 153; r < EPAD; ++r) {
    ent_h[((size_t)b * EPAD + r) * H_ + h] = (__bf16)0.f;
    ent_l[((size_t)b * EPAD + r) * H_ + h] = (__bf16)0.f;
  }
}

// ---------------------------------------------------------------------------
// Stage 3: att = softmax(sub @ ent^T) via split-bf16 MFMA.
// Grid = B*2 (2 blocks/batch, 48 rows each), 192 thr (3 waves).
// Wave = 16 rows x 160 cols = 1x10 fragments. BK=64 GL16 staging.
// ---------------------------------------------------------------------------
__global__ __launch_bounds__(192) void attn_mfma_kernel(
    const __bf16* __restrict__ sub_h, const __bf16* __restrict__ sub_l,
    const __bf16* __restrict__ ent_h, const __bf16* __restrict__ ent_l,
    float* __restrict__ out) {
  __shared__ __align__(16) char smem[53248];
  char* sSh = smem;           // [48][64] bf16: 6 KB
  char* sSl = smem + 6144;    // 6 KB
  char* sEh = smem + 12288;   // [160][64] bf16: 20 KB
  char* sEl = smem + 32768;   // 20 KB

  const int tid = threadIdx.x;
  const int wid = tid >> 6;
  const int lane = tid & 63;
  const int b = blockIdx.x >> 1;
  const int half = blockIdx.x & 1;

  const __bf16* Sh_g = sub_h + ((size_t)b * WSEG + half * 48) * H_;
  const __bf16* Sl_g = sub_l + ((size_t)b * WSEG + half * 48) * H_;
  const __bf16* Eh_g = ent_h + (size_t)b * EPAD * H_;
  const __bf16* El_g = ent_l + (size_t)b * EPAD * H_;

  const int rsub = lane >> 3;
  const int csrc = (lane & 7) ^ rsub;

  const int arow0 = wid * 16 + (lane & 15);
  const int brow0 = lane & 15;
  const int cbase = (lane >> 4) * 16;
  const int sw = (lane & 7) << 4;

  f32x4 acc[10] = {};

#pragma unroll 1
  for (int kt = 0; kt < H_ / 64; ++kt) {
    __syncthreads();
    const size_t kofs = (size_t)kt * 64 + (size_t)csrc * 8;
    // 52 staging instrs: [0,6)=sub_h [6,12)=sub_l [12,32)=ent_h [32,52)=ent_l
#pragma unroll
    for (int j = 0; j < 18; ++j) {
      const int ig = wid * 18 + j;
      if (ig < 6) {
        GL16(Sh_g + (size_t)(ig * 8 + rsub) * H_ + kofs, sSh + ig * 1024);
      } else if (ig < 12) {
        const int i = ig - 6;
        GL16(Sl_g + (size_t)(i * 8 + rsub) * H_ + kofs, sSl + i * 1024);
      } else if (ig < 32) {
        const int i = ig - 12;
        GL16(Eh_g + (size_t)(i * 8 + rsub) * H_ + kofs, sEh + i * 1024);
      } else if (ig < 52) {
        const int i = ig - 32;
        GL16(El_g + (size_t)(i * 8 + rsub) * H_ + kofs, sEl + i * 1024);
      }
    }
    __syncthreads();

#pragma unroll
    for (int ks = 0; ks < 2; ++ks) {
      const int cc = ((cbase + ks * 64) ^ sw);
      const int aoff = arow0 * 128 + cc;
      const bf16x8 ah = *(const bf16x8*)(sSh + aoff);
      const bf16x8 al_ = *(const bf16x8*)(sSl + aoff);
#pragma unroll
      for (int ni = 0; ni < 10; ++ni) {
        const int off = (brow0 + ni * 16) * 128 + cc;
        const bf16x8 bh = *(const bf16x8*)(sEh + off);
        const bf16x8 bl_ = *(const bf16x8*)(sEl + off);
        acc[ni] = __builtin_amdgcn_mfma_f32_16x16x32_bf16(ah, bh, acc[ni], 0,
                                                          0, 0);
        acc[ni] = __builtin_amdgcn_mfma_f32_16x16x32_bf16(ah, bl_, acc[ni], 0,
                                                          0, 0);
        acc[ni] = __builtin_amdgcn_mfma_f32_16x16x32_bf16(al_, bh, acc[ni], 0,
                                                          0, 0);
      }
    }
  }

  // logits -> LDS (reuse staging buffer)
  __syncthreads();
  float (*lg)[EPAD] = (float(*)[EPAD])smem;  // 48*160*4 = 30720 B
  const int rowb = wid * 16 + (lane >> 4) * 4;
  const int colb = lane & 15;
#pragma unroll
  for (int ni = 0; ni < 10; ++ni) {
    const f32x4 v = acc[ni];
#pragma unroll
    for (int r = 0; r < 4; ++r) lg[rowb + r][colb + ni * 16] = v[r];
  }
  __syncthreads();

  for (int r = wid; r < 48; r += 3) {
    const float x0 = lg[r][lane];
    const float x1 = lg[r][lane + 64];
    const bool has2 = (lane + 128) < ESEG;
    const float x2 = has2 ? lg[r][lane + 128] : -INFINITY;
    float m = fmaxf(fmaxf(x0, x1), x2);
#pragma unroll
    for (int off = 32; off >= 1; off >>= 1) m = fmaxf(m, __shfl_xor(m, off, 64));
    const float p0 = expf(x0 - m);
    const float p1 = expf(x1 - m);
    const float p2 = has2 ? expf(x2 - m) : 0.f;
    float ssum = p0 + p1 + p2;
#pragma unroll
    for (int off = 32; off >= 1; off >>= 1) ssum += __shfl_xor(ssum, off, 64);
    const float inv = 1.f / ssum;
    float* ob = out + ((size_t)(b * WSEG + half * 48 + r)) * ESEG;
    ob[lane] = p0 * inv;
    ob[lane + 64] = p1 * inv;
    if (has2) ob[lane + 128] = p2 * inv;
  }
}

// ---------------------------------------------------------------------------
extern "C" void kernel_launch(void* const* d_in, const int* in_sizes, int n_in,
                              void* d_out, int out_size, void* d_ws,
                              size_t ws_size, hipStream_t stream) {
  const float* q = (const float*)d_in[0];
  const float* Wsub = (const float*)d_in[1];
  const float* Wtab = (const float*)d_in[2];
  const float* Wcol = (const float*)d_in[3];
  const float* ne = (const float*)d_in[4];
  const int* wseg = (const int*)d_in[5];
  const int* tseg = (const int*)d_in[6];
  const int* cseg = (const int*)d_in[7];
  float* out = (float*)d_out;

  // flat workspace layout (ws_size ~512MB per profile; total used ~105MB)
  char* w = (char*)d_ws;
  __bf16* Ah = (__bf16*)(w);                 // 32,505,856
  __bf16* Al = (__bf16*)(w + 32505856);      // 32,505,856
  __bf16* ent_h = (__bf16*)(w + 65011712);   // 10,485,760
  __bf16* ent_l = (__bf16*)(w + 75497472);   // 10,485,760
  __bf16* Wth = (__bf16*)(w + 85983232);     //  3,145,728
  __bf16* Wtl = (__bf16*)(w + 89128960);     //  3,145,728
  __bf16* sub_h = (__bf16*)(w + 92274688);   //  6,291,456
  __bf16* sub_l = (__bf16*)(w + 98566144);   //  6,291,456
  int* lw = (int*)(w + 104857600);           //    131,072
  int* lt = (int*)(w + 104988672);
  int* lc = (int*)(w + 105119744);
  int* meta = (int*)(w + 105250816);         // ends ~105.3MB

  build_csr_kernel<<<B_, 512, 0, stream>>>(wseg, tseg, cseg, lw, lt, lc, meta);
  gather_onepass_kernel<<<dim3(32, B_), 256, 0, stream>>>(q, lw, lt, lc, meta,
                                                          Ah, Al);
  prep_w_kernel<<<dim3(8, 16, 3), 256, 0, stream>>>(Wsub, Wtab, Wcol, Wth,
                                                    Wtl);
  gemm3_kernel<<<dim3(4, 124), 256, 0, stream>>>(Ah, Al, Wth, Wtl, sub_h,
                                                 sub_l, ent_h, ent_l, 0);
  ne_fill_kernel<<<B_, 512, 0, stream>>>(ne, ent_h, ent_l);
  attn_mfma_kernel<<<B_ * 2, 192, 0, stream>>>(sub_h, sub_l, ent_h, ent_l,
                                               out);
}

// Round 7
// 158.716 us; speedup vs baseline: 1.9441x; 1.9441x over previous
//
#include <hip/hip_runtime.h>
#include <hip/hip_bf16.h>
#include <math.h>

#define B_ 64
#define S_ 512
#define D_ 1024
#define H_ 512
#define WSEG 96
#define TSEG 24
#define CSEG 128
#define NSEG (WSEG + TSEG + CSEG) /* 248 */
#define ESEG (TSEG + CSEG + 1)    /* 153 */
#define EPAD 160                  /* ent rows padded per batch */

typedef __bf16 bf16x8 __attribute__((ext_vector_type(8)));
typedef __bf16 bf16x4 __attribute__((ext_vector_type(4)));
typedef float f32x4 __attribute__((ext_vector_type(4)));

#define GL16(g, l)                                                      \
  __builtin_amdgcn_global_load_lds(                                     \
      (const __attribute__((address_space(1))) void*)(g),               \
      (__attribute__((address_space(3))) void*)(l), 16, 0, 0)

__device__ inline float tanh_fast(float x) {
  const float xc = fminf(12.f, fmaxf(-12.f, x));
  const float e = __expf(2.f * xc);
  return (e - 1.f) * __builtin_amdgcn_rcpf(e + 1.f);
}

// ---------------------------------------------------------------------------
// Stage 1a: build CSR token lists per (b, segtype, seg). One block per b.
// ---------------------------------------------------------------------------
__global__ __launch_bounds__(512) void build_csr_kernel(
    const int* __restrict__ wseg, const int* __restrict__ tseg,
    const int* __restrict__ cseg, int* __restrict__ lw, int* __restrict__ lt,
    int* __restrict__ lc, int* __restrict__ meta) {
  __shared__ int wid[S_], tid_[S_], cid[S_];
  __shared__ int cw[WSEG], ct[TSEG], cc[CSEG];
  const int t = threadIdx.x;
  const int b = blockIdx.x;

  const int myw = wseg[b * S_ + t];
  const int myt = tseg[b * S_ + t];
  const int myc = cseg[b * S_ + t];
  wid[t] = myw;
  tid_[t] = myt;
  cid[t] = myc;
  if (t < WSEG) cw[t] = 0;
  if (t < TSEG) ct[t] = 0;
  if (t < CSEG) cc[t] = 0;
  __syncthreads();

  atomicAdd(&cw[myw], 1);
  atomicAdd(&ct[myt], 1);
  atomicAdd(&cc[myc], 1);
  __syncthreads();

  if (t == 0) {
    int r = 0;
    for (int i = 0; i < WSEG; ++i) {
      const int c = cw[i];
      meta[b * NSEG + i] = r | (c << 16);
      cw[i] = r;
      r += c;
    }
    r = 0;
    for (int i = 0; i < TSEG; ++i) {
      const int c = ct[i];
      meta[b * NSEG + WSEG + i] = r | (c << 16);
      ct[i] = r;
      r += c;
    }
    r = 0;
    for (int i = 0; i < CSEG; ++i) {
      const int c = cc[i];
      meta[b * NSEG + WSEG + TSEG + i] = r | (c << 16);
      cc[i] = r;
      r += c;
    }
  }
  __syncthreads();

  int rw = 0, rt = 0, rc = 0;
  for (int s = 0; s < S_; ++s) {
    const int below = (s < t) ? 1 : 0;
    rw += below & (wid[s] == myw);
    rt += below & (tid_[s] == myt);
    rc += below & (cid[s] == myc);
  }
  lw[b * S_ + cw[myw] + rw] = t;
  lt[b * S_ + ct[myt] + rt] = t;
  lc[b * S_ + cc[myc] + rc] = t;
}

// ---------------------------------------------------------------------------
// Stage 1b: per-row gather-sum -> A split bf16 (hi + lo). One block per A row
// (B*248 blocks, 256 thr). R5's one-pass variant was serial-latency-bound
// (215us); this per-row form is latency-tolerant (15872 blocks TLP, streams
// whole 4KB q rows). T1 bijective XCD swizzle: 248 consecutive logical blocks
// share one batch's 2MB q slice -> pin them to one XCD so the 3x logical
// re-read hits that XCD's 4MB L2.
// ---------------------------------------------------------------------------
__global__ __launch_bounds__(256) void gather_rows_kernel(
    const float* __restrict__ q, const int* __restrict__ lw,
    const int* __restrict__ lt, const int* __restrict__ lc,
    const int* __restrict__ meta, __bf16* __restrict__ Ah,
    __bf16* __restrict__ Al) {
  __shared__ int slist[S_];
  const int t = threadIdx.x;
  // XCD swizzle: launched bid -> logical row id (nwg = 15872 = 8 * 1984)
  const int bid = blockIdx.x;
  const int r = (bid & 7) * (B_ * NSEG / 8) + (bid >> 3);
  const int b = r / NSEG;
  const int seg = r % NSEG;

  const int m = meta[r];
  const int start = m & 0xFFFF;
  const int count = m >> 16;

  const int* list;
  int arow;
  if (seg < WSEG) {
    list = lw;
    arow = b * WSEG + seg;
  } else if (seg < WSEG + TSEG) {
    list = lt;
    arow = B_ * WSEG + b * TSEG + (seg - WSEG);
  } else {
    list = lc;
    arow = B_ * (WSEG + TSEG) + b * CSEG + (seg - WSEG - TSEG);
  }

  for (int i = t; i < count; i += 256) slist[i] = list[b * S_ + start + i];
  __syncthreads();

  const float* qb = q + (size_t)b * S_ * D_;
  float4 acc = make_float4(0.f, 0.f, 0.f, 0.f);
  int i = 0;
  for (; i + 2 <= count; i += 2) {
    const float4 a = *(const float4*)(qb + (size_t)slist[i] * D_ + (t << 2));
    const float4 c =
        *(const float4*)(qb + (size_t)slist[i + 1] * D_ + (t << 2));
    acc.x += a.x + c.x;
    acc.y += a.y + c.y;
    acc.z += a.z + c.z;
    acc.w += a.w + c.w;
  }
  if (i < count) {
    const float4 a = *(const float4*)(qb + (size_t)slist[i] * D_ + (t << 2));
    acc.x += a.x;
    acc.y += a.y;
    acc.z += a.z;
    acc.w += a.w;
  }
  const __bf16 h0 = (__bf16)acc.x, h1 = (__bf16)acc.y, h2 = (__bf16)acc.z,
               h3 = (__bf16)acc.w;
  const bf16x4 hv = {h0, h1, h2, h3};
  const bf16x4 lv = {(__bf16)(acc.x - (float)h0), (__bf16)(acc.y - (float)h1),
                     (__bf16)(acc.z - (float)h2), (__bf16)(acc.w - (float)h3)};
  *(bf16x4*)(Ah + (size_t)arow * D_ + (t << 2)) = hv;
  *(bf16x4*)(Al + (size_t)arow * D_ + (t << 2)) = lv;
}

// ---------------------------------------------------------------------------
// Stage 1c: transpose weights -> Wt hi/lo bf16 [3][512][1024].
// ---------------------------------------------------------------------------
__global__ __launch_bounds__(256) void prep_w_kernel(
    const float* __restrict__ Ws, const float* __restrict__ Wt_,
    const float* __restrict__ Wc, __bf16* __restrict__ Wth,
    __bf16* __restrict__ Wtl) {
  __shared__ float tile[64][65];
  const int z = blockIdx.z;
  const float* W = (z == 0) ? Ws : ((z == 1) ? Wt_ : Wc);
  const int k0 = blockIdx.y * 64, n0 = blockIdx.x * 64;
  const int tx = threadIdx.x & 63, ty = threadIdx.x >> 6;

#pragma unroll
  for (int i = 0; i < 16; ++i) {
    const int kl = i * 4 + ty;
    tile[kl][tx] = W[(size_t)(k0 + kl) * H_ + n0 + tx];
  }
  __syncthreads();
  __bf16* oh = Wth + (size_t)z * H_ * D_;
  __bf16* ol = Wtl + (size_t)z * H_ * D_;
#pragma unroll
  for (int i = 0; i < 16; ++i) {
    const int nl = i * 4 + ty;
    const float v = tile[tx][nl];
    const __bf16 h = (__bf16)v;
    oh[(size_t)(n0 + nl) * D_ + k0 + tx] = h;
    ol[(size_t)(n0 + nl) * D_ + k0 + tx] = (__bf16)(v - (float)h);
  }
}

// ---------------------------------------------------------------------------
// Stage 2: split-bf16 MFMA GEMM, 128x128 tile, BK=64, tanh epilogue.
// SINGLE launch over all 15872 A rows.
// ---------------------------------------------------------------------------
__global__ __launch_bounds__(256) void gemm3_kernel(
    const __bf16* __restrict__ Ah, const __bf16* __restrict__ Al,
    const __bf16* __restrict__ Wth, const __bf16* __restrict__ Wtl,
    __bf16* __restrict__ sub_h, __bf16* __restrict__ sub_l,
    __bf16* __restrict__ ent_h, __bf16* __restrict__ ent_l, int m_offset) {
  __shared__ __align__(16) char smem[65536];
  char* sAh = smem;
  char* sAl = smem + 16384;
  char* sBh = smem + 32768;
  char* sBl = smem + 49152;

  const int tid = threadIdx.x;
  const int wid = tid >> 6;
  const int lane = tid & 63;
  const int m0 = m_offset + blockIdx.y * 128;
  const int n0 = blockIdx.x * 128;
  const int id = (m0 < B_ * WSEG) ? 0 : ((m0 < B_ * (WSEG + TSEG)) ? 1 : 2);

  const __bf16* Bh_g = Wth + (size_t)id * H_ * D_ + (size_t)n0 * D_;
  const __bf16* Bl_g = Wtl + (size_t)id * H_ * D_ + (size_t)n0 * D_;
  const __bf16* Ah_g = Ah + (size_t)m0 * D_;
  const __bf16* Al_g = Al + (size_t)m0 * D_;

  const int rsub = lane >> 3;
  const int csrc = (lane & 7) ^ rsub;

  const int wr = wid >> 1, wc = wid & 1;
  const int arow0 = wr * 64 + (lane & 15);
  const int brow0 = wc * 64 + (lane & 15);
  const int cbase = (lane >> 4) * 16;
  const int sw = (lane & 7) << 4;

  f32x4 acc[4][4] = {};

#pragma unroll 1
  for (int kt = 0; kt < D_ / 64; ++kt) {
    __syncthreads();
    const size_t kofs = (size_t)kt * 64 + (size_t)csrc * 8;
#pragma unroll
    for (int j = 0; j < 4; ++j) {
      const int i = wid * 4 + j;
      const size_t grow = (size_t)(i * 8 + rsub) * D_ + kofs;
      GL16(Ah_g + grow, sAh + i * 1024);
      GL16(Al_g + grow, sAl + i * 1024);
      GL16(Bh_g + grow, sBh + i * 1024);
      GL16(Bl_g + grow, sBl + i * 1024);
    }
    __syncthreads();

#pragma unroll
    for (int ks = 0; ks < 2; ++ks) {
      const int cc = ((cbase + ks * 64) ^ sw);
      bf16x8 ah[4], al_[4], bh[4], bl_[4];
#pragma unroll
      for (int mi = 0; mi < 4; ++mi) {
        const int off = (arow0 + mi * 16) * 128 + cc;
        ah[mi] = *(const bf16x8*)(sAh + off);
        al_[mi] = *(const bf16x8*)(sAl + off);
      }
#pragma unroll
      for (int ni = 0; ni < 4; ++ni) {
        const int off = (brow0 + ni * 16) * 128 + cc;
        bh[ni] = *(const bf16x8*)(sBh + off);
        bl_[ni] = *(const bf16x8*)(sBl + off);
      }
#pragma unroll
      for (int mi = 0; mi < 4; ++mi)
#pragma unroll
        for (int ni = 0; ni < 4; ++ni) {
          acc[mi][ni] = __builtin_amdgcn_mfma_f32_16x16x32_bf16(
              ah[mi], bh[ni], acc[mi][ni], 0, 0, 0);
          acc[mi][ni] = __builtin_amdgcn_mfma_f32_16x16x32_bf16(
              ah[mi], bl_[ni], acc[mi][ni], 0, 0, 0);
          acc[mi][ni] = __builtin_amdgcn_mfma_f32_16x16x32_bf16(
              al_[mi], bh[ni], acc[mi][ni], 0, 0, 0);
        }
    }
  }

  const int rowb = m0 + wr * 64 + (lane >> 4) * 4;
  const int colb = n0 + wc * 64 + (lane & 15);
#pragma unroll
  for (int mi = 0; mi < 4; ++mi)
#pragma unroll
    for (int ni = 0; ni < 4; ++ni) {
      const f32x4 v = acc[mi][ni];
      const int col = colb + ni * 16;
#pragma unroll
      for (int r = 0; r < 4; ++r) {
        const int row = rowb + mi * 16 + r;
        const float val = tanh_fast(v[r]);
        const __bf16 h = (__bf16)val;
        const __bf16 l = (__bf16)(val - (float)h);
        size_t oix;
        __bf16 *oh, *ol;
        if (id == 0) {
          oix = (size_t)row * H_ + col;
          oh = sub_h;
          ol = sub_l;
        } else if (id == 1) {
          const int lr = row - B_ * WSEG;
          const int bb = lr / TSEG;
          const int rr = lr - bb * TSEG;
          oix = ((size_t)bb * EPAD + rr) * H_ + col;
          oh = ent_h;
          ol = ent_l;
        } else {
          const int lr = row - B_ * (WSEG + TSEG);
          const int bb = lr >> 7;
          const int rr = lr & 127;
          oix = ((size_t)bb * EPAD + TSEG + rr) * H_ + col;
          oh = ent_h;
          ol = ent_l;
        }
        oh[oix] = h;
        ol[oix] = l;
      }
    }
}

// Stage 2b: ent row 152 = no_entry (hi/lo, raw); rows 153..159 zeroed.
__global__ __launch_bounds__(512) void ne_fill_kernel(
    const float* __restrict__ ne, __bf16* __restrict__ ent_h,
    __bf16* __restrict__ ent_l) {
  const int h = threadIdx.x;
  const int b = blockIdx.x;
  const float v = ne[h];
  const __bf16 hi = (__bf16)v;
  const __bf16 lo = (__bf16)(v - (float)hi);
  ent_h[((size_t)b * EPAD + 152) * H_ + h] = hi;
  ent_l[((size_t)b * EPAD + 152) * H_ + h] = lo;
#pragma unroll
  for (int r = 153; r < EPAD; ++r) {
    ent_h[((size_t)b * EPAD + r) * H_ + h] = (__bf16)0.f;
    ent_l[((size_t)b * EPAD + r) * H_ + h] = (__bf16)0.f;
  }
}

// ---------------------------------------------------------------------------
// Stage 3: att = softmax(sub @ ent^T) via split-bf16 MFMA.
// Grid = B*2 (2 blocks/batch, 48 rows each), 192 thr (3 waves).
// ---------------------------------------------------------------------------
__global__ __launch_bounds__(192) void attn_mfma_kernel(
    const __bf16* __restrict__ sub_h, const __bf16* __restrict__ sub_l,
    const __bf16* __restrict__ ent_h, const __bf16* __restrict__ ent_l,
    float* __restrict__ out) {
  __shared__ __align__(16) char smem[53248];
  char* sSh = smem;           // [48][64] bf16: 6 KB
  char* sSl = smem + 6144;    // 6 KB
  char* sEh = smem + 12288;   // [160][64] bf16: 20 KB
  char* sEl = smem + 32768;   // 20 KB

  const int tid = threadIdx.x;
  const int wid = tid >> 6;
  const int lane = tid & 63;
  const int b = blockIdx.x >> 1;
  const int half = blockIdx.x & 1;

  const __bf16* Sh_g = sub_h + ((size_t)b * WSEG + half * 48) * H_;
  const __bf16* Sl_g = sub_l + ((size_t)b * WSEG + half * 48) * H_;
  const __bf16* Eh_g = ent_h + (size_t)b * EPAD * H_;
  const __bf16* El_g = ent_l + (size_t)b * EPAD * H_;

  const int rsub = lane >> 3;
  const int csrc = (lane & 7) ^ rsub;

  const int arow0 = wid * 16 + (lane & 15);
  const int brow0 = lane & 15;
  const int cbase = (lane >> 4) * 16;
  const int sw = (lane & 7) << 4;

  f32x4 acc[10] = {};

#pragma unroll 1
  for (int kt = 0; kt < H_ / 64; ++kt) {
    __syncthreads();
    const size_t kofs = (size_t)kt * 64 + (size_t)csrc * 8;
#pragma unroll
    for (int j = 0; j < 18; ++j) {
      const int ig = wid * 18 + j;
      if (ig < 6) {
        GL16(Sh_g + (size_t)(ig * 8 + rsub) * H_ + kofs, sSh + ig * 1024);
      } else if (ig < 12) {
        const int i = ig - 6;
        GL16(Sl_g + (size_t)(i * 8 + rsub) * H_ + kofs, sSl + i * 1024);
      } else if (ig < 32) {
        const int i = ig - 12;
        GL16(Eh_g + (size_t)(i * 8 + rsub) * H_ + kofs, sEh + i * 1024);
      } else if (ig < 52) {
        const int i = ig - 32;
        GL16(El_g + (size_t)(i * 8 + rsub) * H_ + kofs, sEl + i * 1024);
      }
    }
    __syncthreads();

#pragma unroll
    for (int ks = 0; ks < 2; ++ks) {
      const int cc = ((cbase + ks * 64) ^ sw);
      const int aoff = arow0 * 128 + cc;
      const bf16x8 ah = *(const bf16x8*)(sSh + aoff);
      const bf16x8 al_ = *(const bf16x8*)(sSl + aoff);
#pragma unroll
      for (int ni = 0; ni < 10; ++ni) {
        const int off = (brow0 + ni * 16) * 128 + cc;
        const bf16x8 bh = *(const bf16x8*)(sEh + off);
        const bf16x8 bl_ = *(const bf16x8*)(sEl + off);
        acc[ni] = __builtin_amdgcn_mfma_f32_16x16x32_bf16(ah, bh, acc[ni], 0,
                                                          0, 0);
        acc[ni] = __builtin_amdgcn_mfma_f32_16x16x32_bf16(ah, bl_, acc[ni], 0,
                                                          0, 0);
        acc[ni] = __builtin_amdgcn_mfma_f32_16x16x32_bf16(al_, bh, acc[ni], 0,
                                                          0, 0);
      }
    }
  }

  __syncthreads();
  float (*lg)[EPAD] = (float(*)[EPAD])smem;  // 48*160*4 = 30720 B
  const int rowb = wid * 16 + (lane >> 4) * 4;
  const int colb = lane & 15;
#pragma unroll
  for (int ni = 0; ni < 10; ++ni) {
    const f32x4 v = acc[ni];
#pragma unroll
    for (int r = 0; r < 4; ++r) lg[rowb + r][colb + ni * 16] = v[r];
  }
  __syncthreads();

  for (int r = wid; r < 48; r += 3) {
    const float x0 = lg[r][lane];
    const float x1 = lg[r][lane + 64];
    const bool has2 = (lane + 128) < ESEG;
    const float x2 = has2 ? lg[r][lane + 128] : -INFINITY;
    float m = fmaxf(fmaxf(x0, x1), x2);
#pragma unroll
    for (int off = 32; off >= 1; off >>= 1) m = fmaxf(m, __shfl_xor(m, off, 64));
    const float p0 = expf(x0 - m);
    const float p1 = expf(x1 - m);
    const float p2 = has2 ? expf(x2 - m) : 0.f;
    float ssum = p0 + p1 + p2;
#pragma unroll
    for (int off = 32; off >= 1; off >>= 1) ssum += __shfl_xor(ssum, off, 64);
    const float inv = 1.f / ssum;
    float* ob = out + ((size_t)(b * WSEG + half * 48 + r)) * ESEG;
    ob[lane] = p0 * inv;
    ob[lane + 64] = p1 * inv;
    if (has2) ob[lane + 128] = p2 * inv;
  }
}

// ---------------------------------------------------------------------------
extern "C" void kernel_launch(void* const* d_in, const int* in_sizes, int n_in,
                              void* d_out, int out_size, void* d_ws,
                              size_t ws_size, hipStream_t stream) {
  const float* q = (const float*)d_in[0];
  const float* Wsub = (const float*)d_in[1];
  const float* Wtab = (const float*)d_in[2];
  const float* Wcol = (const float*)d_in[3];
  const float* ne = (const float*)d_in[4];
  const int* wseg = (const int*)d_in[5];
  const int* tseg = (const int*)d_in[6];
  const int* cseg = (const int*)d_in[7];
  float* out = (float*)d_out;

  // flat workspace layout (~105MB of the ~512MB ws)
  char* w = (char*)d_ws;
  __bf16* Ah = (__bf16*)(w);                 // 32,505,856
  __bf16* Al = (__bf16*)(w + 32505856);      // 32,505,856
  __bf16* ent_h = (__bf16*)(w + 65011712);   // 10,485,760
  __bf16* ent_l = (__bf16*)(w + 75497472);   // 10,485,760
  __bf16* Wth = (__bf16*)(w + 85983232);     //  3,145,728
  __bf16* Wtl = (__bf16*)(w + 89128960);     //  3,145,728
  __bf16* sub_h = (__bf16*)(w + 92274688);   //  6,291,456
  __bf16* sub_l = (__bf16*)(w + 98566144);   //  6,291,456
  int* lw = (int*)(w + 104857600);
  int* lt = (int*)(w + 104988672);
  int* lc = (int*)(w + 105119744);
  int* meta = (int*)(w + 105250816);

  build_csr_kernel<<<B_, 512, 0, stream>>>(wseg, tseg, cseg, lw, lt, lc, meta);
  gather_rows_kernel<<<B_ * NSEG, 256, 0, stream>>>(q, lw, lt, lc, meta, Ah,
                                                    Al);
  prep_w_kernel<<<dim3(8, 16, 3), 256, 0, stream>>>(Wsub, Wtab, Wcol, Wth,
                                                    Wtl);
  gemm3_kernel<<<dim3(4, 124), 256, 0, stream>>>(Ah, Al, Wth, Wtl, sub_h,
                                                 sub_l, ent_h, ent_l, 0);
  ne_fill_kernel<<<B_, 512, 0, stream>>>(ne, ent_h, ent_l);
  attn_mfma_kernel<<<B_ * 2, 192, 0, stream>>>(sub_h, sub_l, ent_h, ent_l,
                                               out);
}